// Round 6
// baseline (75.164 us; speedup 1.0000x reference)
//
#include <hip/hip_runtime.h>
#include <hip/hip_fp16.h>

// out[e] = (dot(h[src],h[dst]) + bias[nid[src]] + bias[nid[dst]]) / (pop[src]*pop[dst])
//
// Pipeline:
//   1) prep       : h f32 -> h16 fp16 (25.6 MB) + nodeinfo {1/pop, bias[nid]}
//   2) blockcount : per-block histogram of 8 src-partitions (no global atomics)
//   3) scan       : single-block exclusive scan over flat [p][b] counts
//                   (gives per-block per-partition offsets AND partition bases)
//   4) scatter    : per-block LDS cursors -> rec[pos] = {src,dst,e}
//   5) edge_score_part : block b handles partition b%8 (round-robin block->XCD),
//                   so src-side gathers stay in that XCD's L2 (shard = 3.2 MB
//                   vs 4 MB L2). dst side remains fabric-random.
//
// Output is deterministic: record order within a partition varies, but each
// edge e is processed exactly once and writes only out[e].

#define NPART 8
#define SCAN_THREADS 1024
#define SCAN_PER_THREAD 16
#define SCAN_CAP (SCAN_THREADS * SCAN_PER_THREAD)   // 16384 flat counters max

union H8 {
    float4  f4;
    __half2 h2[4];
};

__device__ inline float dot8(const H8& a, const H8& b) {
    float s = 0.0f;
#pragma unroll
    for (int k = 0; k < 4; ++k) {
        float2 fa = __half22float2(a.h2[k]);
        float2 fb = __half22float2(b.h2[k]);
        s += fa.x * fb.x + fa.y * fb.y;
    }
    return s;
}

__global__ __launch_bounds__(256) void prep_kernel(
    const float* __restrict__ h,
    __half*      __restrict__ h16,
    const float* __restrict__ pop,
    const float* __restrict__ bias,
    const int*   __restrict__ nid,
    float2*      __restrict__ nodeinfo,
    int n_elems, int n_nodes, int conv_blocks)
{
    if (blockIdx.x < (unsigned)conv_blocks) {
        int i = blockIdx.x * blockDim.x + threadIdx.x;
        int base = i * 8;
        if (base < n_elems) {
            const float4 f0 = *reinterpret_cast<const float4*>(h + base);
            const float4 f1 = *reinterpret_cast<const float4*>(h + base + 4);
            H8 o;
            o.h2[0] = __floats2half2_rn(f0.x, f0.y);
            o.h2[1] = __floats2half2_rn(f0.z, f0.w);
            o.h2[2] = __floats2half2_rn(f1.x, f1.y);
            o.h2[3] = __floats2half2_rn(f1.z, f1.w);
            *reinterpret_cast<float4*>(h16 + base) = o.f4;
        }
    } else {
        int i = (blockIdx.x - conv_blocks) * blockDim.x + threadIdx.x;
        if (i < n_nodes) {
            nodeinfo[i] = make_float2(1.0f / pop[i], bias[nid[i]]);
        }
    }
}

// 2) per-block partition counts -> blockcounts[p*nb + b]
__global__ __launch_bounds__(256) void blockcount_kernel(
    const int* __restrict__ src,
    unsigned*  __restrict__ blockcounts,
    int n_edges, int nb, int part_div)
{
    __shared__ unsigned hist[NPART];
    if (threadIdx.x < NPART) hist[threadIdx.x] = 0u;
    __syncthreads();

    int e = blockIdx.x * 256 + threadIdx.x;
    if (e < n_edges) {
        int p = src[e] / part_div;
        atomicAdd(&hist[p], 1u);
    }
    __syncthreads();

    if (threadIdx.x < NPART)
        blockcounts[threadIdx.x * nb + blockIdx.x] = hist[threadIdx.x];
}

// 3) exclusive scan over n = NPART*nb flat counters, single block.
//    Flat order [p][b] means offs[p*nb] is the base of partition p.
__global__ __launch_bounds__(SCAN_THREADS) void scan_kernel(
    const unsigned* __restrict__ counts,
    unsigned*       __restrict__ offs,
    int n)
{
    __shared__ unsigned part[SCAN_THREADS];
    const int t = threadIdx.x;
    const int base = t * SCAN_PER_THREAD;

    unsigned v[SCAN_PER_THREAD];
    unsigned s = 0;
#pragma unroll
    for (int i = 0; i < SCAN_PER_THREAD; ++i) {
        unsigned x = (base + i < n) ? counts[base + i] : 0u;
        v[i] = s;
        s += x;
    }
    part[t] = s;
    __syncthreads();

    for (int off = 1; off < SCAN_THREADS; off <<= 1) {
        unsigned u = (t >= off) ? part[t - off] : 0u;
        __syncthreads();
        part[t] += u;
        __syncthreads();
    }

    unsigned tb = (t == 0) ? 0u : part[t - 1];
#pragma unroll
    for (int i = 0; i < SCAN_PER_THREAD; ++i) {
        if (base + i < n) offs[base + i] = tb + v[i];
    }
}

// 4) scatter edges into partition-sorted rec[] using per-block LDS cursors
__global__ __launch_bounds__(256) void scatter_kernel(
    const int* __restrict__ src,
    const int* __restrict__ dst,
    const unsigned* __restrict__ offs,
    int4*      __restrict__ rec,
    int n_edges, int nb, int part_div)
{
    __shared__ unsigned cur[NPART];
    if (threadIdx.x < NPART)
        cur[threadIdx.x] = offs[threadIdx.x * nb + blockIdx.x];
    __syncthreads();

    int e = blockIdx.x * 256 + threadIdx.x;
    if (e < n_edges) {
        int si = src[e];
        int p  = si / part_div;
        unsigned pos = atomicAdd(&cur[p], 1u);
        rec[pos] = make_int4(si, dst[e], e, 0);
    }
}

// 5) partitioned edge scorer: block b -> partition b%8 (round-robin XCD)
__global__ __launch_bounds__(256) void edge_score_part_kernel(
    const __half*   __restrict__ h16,
    const float2*   __restrict__ nodeinfo,
    const int4*     __restrict__ rec,
    const unsigned* __restrict__ offs,
    float*          __restrict__ out,
    int n_edges, int nb)
{
    const int p = blockIdx.x & (NPART - 1);   // XCD affinity
    const int c = blockIdx.x >> 3;

    const unsigned pstart = offs[p * nb];
    const unsigned pend   = (p + 1 < NPART) ? offs[(p + 1) * nb]
                                            : (unsigned)n_edges;

    const int grp  = threadIdx.x >> 3;        // 32 edges per block
    const int lane = threadIdx.x & 7;

    const unsigned k = pstart + (unsigned)c * 32u + (unsigned)grp;
    if (k >= pend) return;

    const int4 r  = rec[k];                   // broadcast within group
    const int  si = r.x;
    const int  di = r.y;

    const __half* ra = h16 + (size_t)si * 128 + lane * 8;
    const __half* rb = h16 + (size_t)di * 128 + lane * 8;

    H8 a0, a1, b0, b1;
    a0.f4 = *reinterpret_cast<const float4*>(ra);
    a1.f4 = *reinterpret_cast<const float4*>(ra + 64);
    b0.f4 = *reinterpret_cast<const float4*>(rb);
    b1.f4 = *reinterpret_cast<const float4*>(rb + 64);

    float part = dot8(a0, b0) + dot8(a1, b1);

    part += __shfl_xor(part, 1);
    part += __shfl_xor(part, 2);
    part += __shfl_xor(part, 4);

    if (lane == 0) {
        const float2 ns = nodeinfo[si];
        const float2 nd = nodeinfo[di];
        __builtin_nontemporal_store((part + ns.y + nd.y) * (ns.x * nd.x),
                                    out + r.z);
    }
}

// ---- fallbacks ----

__global__ __launch_bounds__(256) void edge_score_f16_kernel(
    const __half* __restrict__ h16,
    const float2* __restrict__ nodeinfo,
    const int*    __restrict__ src,
    const int*    __restrict__ dst,
    float*        __restrict__ out,
    int n_edges)
{
    const int gtid = blockIdx.x * blockDim.x + threadIdx.x;
    const int e    = gtid >> 3;
    const int lane = threadIdx.x & 7;
    if (e >= n_edges) return;

    const int si = src[e];
    const int di = dst[e];
    const __half* ra = h16 + (size_t)si * 128 + lane * 8;
    const __half* rb = h16 + (size_t)di * 128 + lane * 8;

    H8 a0, a1, b0, b1;
    a0.f4 = *reinterpret_cast<const float4*>(ra);
    a1.f4 = *reinterpret_cast<const float4*>(ra + 64);
    b0.f4 = *reinterpret_cast<const float4*>(rb);
    b1.f4 = *reinterpret_cast<const float4*>(rb + 64);

    float part = dot8(a0, b0) + dot8(a1, b1);

    part += __shfl_xor(part, 1);
    part += __shfl_xor(part, 2);
    part += __shfl_xor(part, 4);

    if (lane == 0) {
        const float2 ns = nodeinfo[si];
        const float2 nd = nodeinfo[di];
        out[e] = (part + ns.y + nd.y) * (ns.x * nd.x);
    }
}

__global__ __launch_bounds__(256) void edge_score_fallback_kernel(
    const float* __restrict__ h,
    const float* __restrict__ pop,
    const float* __restrict__ bias,
    const int*   __restrict__ src,
    const int*   __restrict__ dst,
    const int*   __restrict__ nid,
    float*       __restrict__ out,
    int n_edges)
{
    const int gtid = blockIdx.x * blockDim.x + threadIdx.x;
    const int e    = gtid >> 4;
    const int lane = threadIdx.x & 15;
    if (e >= n_edges) return;

    const int si = src[e];
    const int di = dst[e];
    const float* ra = h + (size_t)si * 128 + lane * 8;
    const float* rb = h + (size_t)di * 128 + lane * 8;
    const float4 a0 = *reinterpret_cast<const float4*>(ra);
    const float4 a1 = *reinterpret_cast<const float4*>(ra + 4);
    const float4 b0 = *reinterpret_cast<const float4*>(rb);
    const float4 b1 = *reinterpret_cast<const float4*>(rb + 4);

    float part = a0.x * b0.x + a0.y * b0.y + a0.z * b0.z + a0.w * b0.w
               + a1.x * b1.x + a1.y * b1.y + a1.z * b1.z + a1.w * b1.w;

    part += __shfl_xor(part, 1);
    part += __shfl_xor(part, 2);
    part += __shfl_xor(part, 4);
    part += __shfl_xor(part, 8);

    if (lane == 0) {
        const float ipw = (1.0f / pop[si]) * (1.0f / pop[di]);
        const float bb  = bias[nid[si]] + bias[nid[di]];
        out[e] = (part + bb) * ipw;
    }
}

extern "C" void kernel_launch(void* const* d_in, const int* in_sizes, int n_in,
                              void* d_out, int out_size, void* d_ws, size_t ws_size,
                              hipStream_t stream) {
    const float* h    = (const float*)d_in[0];
    const float* pop  = (const float*)d_in[1];
    const float* bias = (const float*)d_in[2];
    const int*   src  = (const int*)d_in[3];
    const int*   dst  = (const int*)d_in[4];
    const int*   nid  = (const int*)d_in[5];
    float*       out  = (float*)d_out;

    const int n_edges = in_sizes[3];
    const int n_nodes = in_sizes[1];
    const int n_elems = in_sizes[0];          // n_nodes * 128

    auto align256 = [](size_t x) { return (x + 255) & ~(size_t)255; };
    const size_t h16_bytes  = align256((size_t)n_elems * sizeof(__half));
    const size_t info_bytes = align256((size_t)n_nodes * sizeof(float2));

    const int nb       = (n_edges + 255) / 256;       // blockcount blocks
    const int n_flat   = NPART * nb;
    const int part_div = (n_nodes + NPART - 1) / NPART;

    const size_t cnt_bytes = align256((size_t)n_flat * sizeof(unsigned));
    const size_t rec_bytes = align256((size_t)n_edges * sizeof(int4));
    const size_t full_bytes = h16_bytes + info_bytes + 2 * cnt_bytes + rec_bytes;

    if (ws_size >= full_bytes && n_flat <= SCAN_CAP) {
        char* wp = (char*)d_ws;
        __half*   h16      = (__half*)wp;    wp += h16_bytes;
        float2*   nodeinfo = (float2*)wp;    wp += info_bytes;
        unsigned* counts   = (unsigned*)wp;  wp += cnt_bytes;
        unsigned* offs     = (unsigned*)wp;  wp += cnt_bytes;
        int4*     rec      = (int4*)wp;

        const int conv_blocks = (n_elems / 8 + 255) / 256;
        const int info_blocks = (n_nodes + 255) / 256;
        prep_kernel<<<conv_blocks + info_blocks, 256, 0, stream>>>(
            h, h16, pop, bias, nid, nodeinfo, n_elems, n_nodes, conv_blocks);

        blockcount_kernel<<<nb, 256, 0, stream>>>(src, counts, n_edges, nb, part_div);

        scan_kernel<<<1, SCAN_THREADS, 0, stream>>>(counts, offs, n_flat);

        scatter_kernel<<<nb, 256, 0, stream>>>(src, dst, offs, rec,
                                               n_edges, nb, part_div);

        // 32 edges per block; per-partition block budget + generous slack
        const int epb  = 256 / 8;                         // 32 edges/block
        const int bpp  = (n_edges + NPART * epb - 1) / (NPART * epb) + 256;
        edge_score_part_kernel<<<bpp * NPART, 256, 0, stream>>>(
            h16, nodeinfo, rec, offs, out, n_edges, nb);
    } else if (ws_size >= h16_bytes + info_bytes) {
        __half* h16      = (__half*)d_ws;
        float2* nodeinfo = (float2*)((char*)d_ws + h16_bytes);

        const int conv_blocks = (n_elems / 8 + 255) / 256;
        const int info_blocks = (n_nodes + 255) / 256;
        prep_kernel<<<conv_blocks + info_blocks, 256, 0, stream>>>(
            h, h16, pop, bias, nid, nodeinfo, n_elems, n_nodes, conv_blocks);

        int grid = ((n_edges * 8) + 255) / 256;
        edge_score_f16_kernel<<<grid, 256, 0, stream>>>(h16, nodeinfo, src, dst,
                                                        out, n_edges);
    } else {
        int grid = ((n_edges * 16) + 255) / 256;
        edge_score_fallback_kernel<<<grid, 256, 0, stream>>>(h, pop, bias, src, dst, nid,
                                                             out, n_edges);
    }
}

// Round 8
// 56.363 us; speedup vs baseline: 1.3336x; 1.3336x over previous
//
#include <hip/hip_runtime.h>
#include <hip/hip_fp16.h>

// out[e] = (dot(h[src],h[dst]) + bias[nid[src]] + bias[nid[dst]]) / (pop[src]*pop[dst])
//
// Two kernels (R5 structure — best measured: 54.9 us):
//   1) prep_kernel: fused
//        - h (f32, 51.2 MB) -> h16 (fp16, 25.6 MB)   [halves random-gather bytes]
//        - nodeinfo[i] = {1/pop[i], bias[nid[i]]}    (800 KB, L2-resident)
//   2) edge_score_f16: 8 lanes/edge; each lane 16 B per row; the group's two
//      loads cover the row's two 128-B lines exactly. fp32 accumulate,
//      3-step shfl_xor reduce. Index loads / out stores nontemporal.
//
// Measured ceilings (R2-R6): gather phase runs at ~6.6-6.8 TB/s fabric
// (= harness fill-kernel speed); convert at streaming ceiling. Sort/partition
// machinery (R4: +65us, R6: +20us) costs more than XCD locality buys — do not
// reintroduce. fp16 absmax 0.25 vs 0.82 threshold; int8/fp8/bf16 fail.
//
// NOTE: __builtin_nontemporal_load requires a native scalar/vector pointer,
// not HIP_vector_type — use an ext_vector_type(4) float alias.

typedef float floatx4 __attribute__((ext_vector_type(4)));

union H8 {
    float4  f4;
    __half2 h2[4];
};

__device__ inline float dot8(const H8& a, const H8& b) {
    float s = 0.0f;
#pragma unroll
    for (int k = 0; k < 4; ++k) {
        float2 fa = __half22float2(a.h2[k]);
        float2 fb = __half22float2(b.h2[k]);
        s += fa.x * fb.x + fa.y * fb.y;
    }
    return s;
}

__global__ __launch_bounds__(256) void prep_kernel(
    const float* __restrict__ h,
    __half*      __restrict__ h16,
    const float* __restrict__ pop,
    const float* __restrict__ bias,
    const int*   __restrict__ nid,
    float2*      __restrict__ nodeinfo,
    int n_elems,                       // n_nodes * 128
    int n_nodes,
    int conv_blocks)                   // blocks devoted to conversion
{
    if (blockIdx.x < (unsigned)conv_blocks) {
        int i = blockIdx.x * blockDim.x + threadIdx.x;
        int base = i * 8;
        if (base < n_elems) {
            // h is single-use: nontemporal, don't pollute L2/L3
            const floatx4* p0 = reinterpret_cast<const floatx4*>(h + base);
            const floatx4* p1 = reinterpret_cast<const floatx4*>(h + base + 4);
            const floatx4 f0 = __builtin_nontemporal_load(p0);
            const floatx4 f1 = __builtin_nontemporal_load(p1);
            H8 o;
            o.h2[0] = __floats2half2_rn(f0.x, f0.y);
            o.h2[1] = __floats2half2_rn(f0.z, f0.w);
            o.h2[2] = __floats2half2_rn(f1.x, f1.y);
            o.h2[3] = __floats2half2_rn(f1.z, f1.w);
            *reinterpret_cast<float4*>(h16 + base) = o.f4;
        }
    } else {
        int i = (blockIdx.x - conv_blocks) * blockDim.x + threadIdx.x;
        if (i < n_nodes) {
            nodeinfo[i] = make_float2(1.0f / pop[i], bias[nid[i]]);
        }
    }
}

__global__ __launch_bounds__(256) void edge_score_f16_kernel(
    const __half* __restrict__ h16,
    const float2* __restrict__ nodeinfo,
    const int*    __restrict__ src,
    const int*    __restrict__ dst,
    float*        __restrict__ out,
    int n_edges)
{
    const int gtid = blockIdx.x * blockDim.x + threadIdx.x;
    const int e    = gtid >> 3;           // one edge per 8 lanes
    const int lane = threadIdx.x & 7;
    if (e >= n_edges) return;

    const int si = __builtin_nontemporal_load(src + e);
    const int di = __builtin_nontemporal_load(dst + e);

    // row = 128 halves = 256 B; group load1 covers line 1, load2 line 2
    const __half* ra = h16 + (size_t)si * 128 + lane * 8;
    const __half* rb = h16 + (size_t)di * 128 + lane * 8;

    H8 a0, a1, b0, b1;
    a0.f4 = *reinterpret_cast<const float4*>(ra);
    a1.f4 = *reinterpret_cast<const float4*>(ra + 64);
    b0.f4 = *reinterpret_cast<const float4*>(rb);
    b1.f4 = *reinterpret_cast<const float4*>(rb + 64);

    float part = dot8(a0, b0) + dot8(a1, b1);

    part += __shfl_xor(part, 1);
    part += __shfl_xor(part, 2);
    part += __shfl_xor(part, 4);

    if (lane == 0) {
        const float2 ns = nodeinfo[si];
        const float2 nd = nodeinfo[di];
        __builtin_nontemporal_store((part + ns.y + nd.y) * (ns.x * nd.x), out + e);
    }
}

// ---- fallback (ws too small): direct f32 path with scalar gathers ----

__global__ __launch_bounds__(256) void edge_score_fallback_kernel(
    const float* __restrict__ h,
    const float* __restrict__ pop,
    const float* __restrict__ bias,
    const int*   __restrict__ src,
    const int*   __restrict__ dst,
    const int*   __restrict__ nid,
    float*       __restrict__ out,
    int n_edges)
{
    const int gtid = blockIdx.x * blockDim.x + threadIdx.x;
    const int e    = gtid >> 4;
    const int lane = threadIdx.x & 15;
    if (e >= n_edges) return;

    const int si = src[e];
    const int di = dst[e];
    const float* ra = h + (size_t)si * 128 + lane * 8;
    const float* rb = h + (size_t)di * 128 + lane * 8;
    const float4 a0 = *reinterpret_cast<const float4*>(ra);
    const float4 a1 = *reinterpret_cast<const float4*>(ra + 4);
    const float4 b0 = *reinterpret_cast<const float4*>(rb);
    const float4 b1 = *reinterpret_cast<const float4*>(rb + 4);

    float part = a0.x * b0.x + a0.y * b0.y + a0.z * b0.z + a0.w * b0.w
               + a1.x * b1.x + a1.y * b1.y + a1.z * b1.z + a1.w * b1.w;

    part += __shfl_xor(part, 1);
    part += __shfl_xor(part, 2);
    part += __shfl_xor(part, 4);
    part += __shfl_xor(part, 8);

    if (lane == 0) {
        const float ipw = (1.0f / pop[si]) * (1.0f / pop[di]);
        const float bb  = bias[nid[si]] + bias[nid[di]];
        out[e] = (part + bb) * ipw;
    }
}

extern "C" void kernel_launch(void* const* d_in, const int* in_sizes, int n_in,
                              void* d_out, int out_size, void* d_ws, size_t ws_size,
                              hipStream_t stream) {
    const float* h    = (const float*)d_in[0];
    const float* pop  = (const float*)d_in[1];
    const float* bias = (const float*)d_in[2];
    const int*   src  = (const int*)d_in[3];
    const int*   dst  = (const int*)d_in[4];
    const int*   nid  = (const int*)d_in[5];
    float*       out  = (float*)d_out;

    const int n_edges = in_sizes[3];
    const int n_nodes = in_sizes[1];
    const int n_elems = in_sizes[0];          // n_nodes * 128

    auto align256 = [](size_t x) { return (x + 255) & ~(size_t)255; };
    const size_t h16_bytes  = align256((size_t)n_elems * sizeof(__half));
    const size_t info_bytes = align256((size_t)n_nodes * sizeof(float2));

    if (ws_size >= h16_bytes + info_bytes) {
        __half* h16      = (__half*)d_ws;
        float2* nodeinfo = (float2*)((char*)d_ws + h16_bytes);

        const int conv_blocks = (n_elems / 8 + 255) / 256;
        const int prep_blocks = (n_nodes + 255) / 256;
        prep_kernel<<<conv_blocks + prep_blocks, 256, 0, stream>>>(
            h, h16, pop, bias, nid, nodeinfo, n_elems, n_nodes, conv_blocks);

        int grid = ((n_edges * 8) + 255) / 256;   // 8 lanes per edge
        edge_score_f16_kernel<<<grid, 256, 0, stream>>>(h16, nodeinfo, src, dst,
                                                        out, n_edges);
    } else {
        int grid = ((n_edges * 16) + 255) / 256;
        edge_score_fallback_kernel<<<grid, 256, 0, stream>>>(h, pop, bias, src, dst, nid,
                                                             out, n_edges);
    }
}

// Round 9
// 54.922 us; speedup vs baseline: 1.3686x; 1.0262x over previous
//
#include <hip/hip_runtime.h>
#include <hip/hip_fp16.h>

// out[e] = (dot(h[src],h[dst]) + bias[nid[src]] + bias[nid[dst]]) / (pop[src]*pop[dst])
//
// Two kernels (R5 structure — best measured: 54.9 us):
//   1) prep_kernel: fused
//        - h (f32, 51.2 MB) -> h16 (fp16, 25.6 MB)   [halves random-gather bytes]
//        - nodeinfo[i] = {1/pop[i], bias[nid[i]]}    (800 KB, L2-resident)
//   2) edge_score_f16: 8 lanes/edge; each lane 16 B per row; the group's two
//      loads cover the row's two 128-B lines exactly. fp32 accumulate,
//      3-step shfl_xor reduce. Index loads / out stores nontemporal.
//
// Measured ceilings (R2-R8): edge gather phase runs at ~6.6-6.8 TB/s
// (= harness fill-kernel speed, the fabric ceiling); convert at streaming
// ceiling. Sort/partition machinery (R4: +65us, R6: +20us) costs more than
// XCD locality buys — do not reintroduce. NT-load on prep's h stream was
// neutral/slightly negative (R8) — plain loads here. fp16 absmax 0.25 vs
// 0.82 threshold; int8/fp8/bf16 projected to fail numerically.

union H8 {
    float4  f4;
    __half2 h2[4];
};

__device__ inline float dot8(const H8& a, const H8& b) {
    float s = 0.0f;
#pragma unroll
    for (int k = 0; k < 4; ++k) {
        float2 fa = __half22float2(a.h2[k]);
        float2 fb = __half22float2(b.h2[k]);
        s += fa.x * fb.x + fa.y * fb.y;
    }
    return s;
}

__global__ __launch_bounds__(256) void prep_kernel(
    const float* __restrict__ h,
    __half*      __restrict__ h16,
    const float* __restrict__ pop,
    const float* __restrict__ bias,
    const int*   __restrict__ nid,
    float2*      __restrict__ nodeinfo,
    int n_elems,                       // n_nodes * 128
    int n_nodes,
    int conv_blocks)                   // blocks devoted to conversion
{
    if (blockIdx.x < (unsigned)conv_blocks) {
        int i = blockIdx.x * blockDim.x + threadIdx.x;
        int base = i * 8;
        if (base < n_elems) {
            const float4 f0 = *reinterpret_cast<const float4*>(h + base);
            const float4 f1 = *reinterpret_cast<const float4*>(h + base + 4);
            H8 o;
            o.h2[0] = __floats2half2_rn(f0.x, f0.y);
            o.h2[1] = __floats2half2_rn(f0.z, f0.w);
            o.h2[2] = __floats2half2_rn(f1.x, f1.y);
            o.h2[3] = __floats2half2_rn(f1.z, f1.w);
            *reinterpret_cast<float4*>(h16 + base) = o.f4;
        }
    } else {
        int i = (blockIdx.x - conv_blocks) * blockDim.x + threadIdx.x;
        if (i < n_nodes) {
            nodeinfo[i] = make_float2(1.0f / pop[i], bias[nid[i]]);
        }
    }
}

__global__ __launch_bounds__(256) void edge_score_f16_kernel(
    const __half* __restrict__ h16,
    const float2* __restrict__ nodeinfo,
    const int*    __restrict__ src,
    const int*    __restrict__ dst,
    float*        __restrict__ out,
    int n_edges)
{
    const int gtid = blockIdx.x * blockDim.x + threadIdx.x;
    const int e    = gtid >> 3;           // one edge per 8 lanes
    const int lane = threadIdx.x & 7;
    if (e >= n_edges) return;

    const int si = __builtin_nontemporal_load(src + e);
    const int di = __builtin_nontemporal_load(dst + e);

    // row = 128 halves = 256 B; group load1 covers line 1, load2 line 2
    const __half* ra = h16 + (size_t)si * 128 + lane * 8;
    const __half* rb = h16 + (size_t)di * 128 + lane * 8;

    H8 a0, a1, b0, b1;
    a0.f4 = *reinterpret_cast<const float4*>(ra);
    a1.f4 = *reinterpret_cast<const float4*>(ra + 64);
    b0.f4 = *reinterpret_cast<const float4*>(rb);
    b1.f4 = *reinterpret_cast<const float4*>(rb + 64);

    float part = dot8(a0, b0) + dot8(a1, b1);

    part += __shfl_xor(part, 1);
    part += __shfl_xor(part, 2);
    part += __shfl_xor(part, 4);

    if (lane == 0) {
        const float2 ns = nodeinfo[si];
        const float2 nd = nodeinfo[di];
        __builtin_nontemporal_store((part + ns.y + nd.y) * (ns.x * nd.x), out + e);
    }
}

// ---- fallback (ws too small): direct f32 path with scalar gathers ----

__global__ __launch_bounds__(256) void edge_score_fallback_kernel(
    const float* __restrict__ h,
    const float* __restrict__ pop,
    const float* __restrict__ bias,
    const int*   __restrict__ src,
    const int*   __restrict__ dst,
    const int*   __restrict__ nid,
    float*       __restrict__ out,
    int n_edges)
{
    const int gtid = blockIdx.x * blockDim.x + threadIdx.x;
    const int e    = gtid >> 4;
    const int lane = threadIdx.x & 15;
    if (e >= n_edges) return;

    const int si = src[e];
    const int di = dst[e];
    const float* ra = h + (size_t)si * 128 + lane * 8;
    const float* rb = h + (size_t)di * 128 + lane * 8;
    const float4 a0 = *reinterpret_cast<const float4*>(ra);
    const float4 a1 = *reinterpret_cast<const float4*>(ra + 4);
    const float4 b0 = *reinterpret_cast<const float4*>(rb);
    const float4 b1 = *reinterpret_cast<const float4*>(rb + 4);

    float part = a0.x * b0.x + a0.y * b0.y + a0.z * b0.z + a0.w * b0.w
               + a1.x * b1.x + a1.y * b1.y + a1.z * b1.z + a1.w * b1.w;

    part += __shfl_xor(part, 1);
    part += __shfl_xor(part, 2);
    part += __shfl_xor(part, 4);
    part += __shfl_xor(part, 8);

    if (lane == 0) {
        const float ipw = (1.0f / pop[si]) * (1.0f / pop[di]);
        const float bb  = bias[nid[si]] + bias[nid[di]];
        out[e] = (part + bb) * ipw;
    }
}

extern "C" void kernel_launch(void* const* d_in, const int* in_sizes, int n_in,
                              void* d_out, int out_size, void* d_ws, size_t ws_size,
                              hipStream_t stream) {
    const float* h    = (const float*)d_in[0];
    const float* pop  = (const float*)d_in[1];
    const float* bias = (const float*)d_in[2];
    const int*   src  = (const int*)d_in[3];
    const int*   dst  = (const int*)d_in[4];
    const int*   nid  = (const int*)d_in[5];
    float*       out  = (float*)d_out;

    const int n_edges = in_sizes[3];
    const int n_nodes = in_sizes[1];
    const int n_elems = in_sizes[0];          // n_nodes * 128

    auto align256 = [](size_t x) { return (x + 255) & ~(size_t)255; };
    const size_t h16_bytes  = align256((size_t)n_elems * sizeof(__half));
    const size_t info_bytes = align256((size_t)n_nodes * sizeof(float2));

    if (ws_size >= h16_bytes + info_bytes) {
        __half* h16      = (__half*)d_ws;
        float2* nodeinfo = (float2*)((char*)d_ws + h16_bytes);

        const int conv_blocks = (n_elems / 8 + 255) / 256;
        const int prep_blocks = (n_nodes + 255) / 256;
        prep_kernel<<<conv_blocks + prep_blocks, 256, 0, stream>>>(
            h, h16, pop, bias, nid, nodeinfo, n_elems, n_nodes, conv_blocks);

        int grid = ((n_edges * 8) + 255) / 256;   // 8 lanes per edge
        edge_score_f16_kernel<<<grid, 256, 0, stream>>>(h16, nodeinfo, src, dst,
                                                        out, n_edges);
    } else {
        int grid = ((n_edges * 16) + 255) / 256;
        edge_score_fallback_kernel<<<grid, 256, 0, stream>>>(h, pop, bias, src, dst, nid,
                                                             out, n_edges);
    }
}